// Round 2
// baseline (188.217 us; speedup 1.0000x reference)
//
#include <hip/hip_runtime.h>

#define T_TOKENS 8192
#define D_MODEL  4096
#define N_EXP    64

// ---------------------------------------------------------------------------
// Kernel 1: partial GEMM, f64 accumulation.
// part[ks][t][e] = sum_{k in slice} (double)h[t][k] * (double)w[e][k]
// grid (128, KS), block 64 (1 wave): 64 tokens x 64 experts per block,
// 8x8 f64 register tile per lane. LDS tiles f32, stored transposed [k][t].
// ---------------------------------------------------------------------------
__global__ __launch_bounds__(64) void k_gemm(const float* __restrict__ h,
                                             const float* __restrict__ w,
                                             double* __restrict__ part,
                                             int ks_len) {
    __shared__ float4 lh[32][16];   // [k][token/4]  8 KB
    __shared__ float4 lw[32][16];   // [k][expert/4] 8 KB

    const int tile = blockIdx.x;          // token tile 0..127
    const int ks   = blockIdx.y;          // k-split id
    const int lane = threadIdx.x;         // 0..63
    const int lt = lane & 7;              // token group (compute)
    const int le = lane >> 3;             // expert group (compute)
    const int rg = lane >> 3;             // row group (staging)
    const int cg = lane & 7;              // col group (staging)
    const int T0 = tile * 64;
    const int k0 = ks * ks_len;

    double acc[8][8];
#pragma unroll
    for (int i = 0; i < 8; ++i)
#pragma unroll
        for (int j = 0; j < 8; ++j) acc[i][j] = 0.0;

    const int iters = ks_len >> 5;        // 32 k per iter
    for (int it = 0; it < iters; ++it) {
        const int kb = k0 + (it << 5);
        __syncthreads();
        float* dh = reinterpret_cast<float*>(lh);
        float* dw = reinterpret_cast<float*>(lw);
#pragma unroll
        for (int r = 0; r < 8; ++r) {
            const int row = rg + 8 * r;   // token row / expert row
            const float4 v = *reinterpret_cast<const float4*>(
                &h[(size_t)(T0 + row) * D_MODEL + kb + cg * 4]);
            dh[(cg * 4 + 0) * 64 + row] = v.x;
            dh[(cg * 4 + 1) * 64 + row] = v.y;
            dh[(cg * 4 + 2) * 64 + row] = v.z;
            dh[(cg * 4 + 3) * 64 + row] = v.w;
            const float4 u = *reinterpret_cast<const float4*>(
                &w[(size_t)row * D_MODEL + kb + cg * 4]);
            dw[(cg * 4 + 0) * 64 + row] = u.x;
            dw[(cg * 4 + 1) * 64 + row] = u.y;
            dw[(cg * 4 + 2) * 64 + row] = u.z;
            dw[(cg * 4 + 3) * 64 + row] = u.w;
        }
        __syncthreads();
#pragma unroll
        for (int k = 0; k < 32; ++k) {
            const float4 a0 = lh[k][lt];
            const float4 a1 = lh[k][lt + 8];
            const float4 b0 = lw[k][le];
            const float4 b1 = lw[k][le + 8];
            const double av[8] = {(double)a0.x, (double)a0.y, (double)a0.z, (double)a0.w,
                                  (double)a1.x, (double)a1.y, (double)a1.z, (double)a1.w};
            const double bv[8] = {(double)b0.x, (double)b0.y, (double)b0.z, (double)b0.w,
                                  (double)b1.x, (double)b1.y, (double)b1.z, (double)b1.w};
#pragma unroll
            for (int i = 0; i < 8; ++i)
#pragma unroll
                for (int j = 0; j < 8; ++j)
                    acc[i][j] = fma(av[i], bv[j], acc[i][j]);
        }
    }

    // tokens: lt*4+(i&3)+(i>>2)*32 ; experts: le*4+(j&3)+(j>>2)*32
    double* base = part + ((size_t)ks * T_TOKENS + T0) * N_EXP;
#pragma unroll
    for (int i = 0; i < 8; ++i) {
        const int t = lt * 4 + (i & 3) + (i >> 2) * 32;
#pragma unroll
        for (int jh = 0; jh < 2; ++jh) {
            const int e = le * 4 + jh * 32;
            double2 o0 = make_double2(acc[i][jh * 4 + 0], acc[i][jh * 4 + 1]);
            double2 o1 = make_double2(acc[i][jh * 4 + 2], acc[i][jh * 4 + 3]);
            *reinterpret_cast<double2*>(&base[(size_t)t * N_EXP + e])     = o0;
            *reinterpret_cast<double2*>(&base[(size_t)t * N_EXP + e + 2]) = o1;
        }
    }
}

// ---------------------------------------------------------------------------
// Kernel 2: per-token softmax + top-8 + per-block expert prob sums.
// block 256 (4 waves), wave handles 4 tokens sequentially, lane = expert.
// Logit sum + top-k ordering in f64 (matches f64 numpy ref); exp/weights f32.
// ---------------------------------------------------------------------------
__global__ __launch_bounds__(256) void k_router(const double* __restrict__ part, int KS,
                                                float* __restrict__ out_idx,
                                                float* __restrict__ out_w,
                                                float* __restrict__ expsum) {
    __shared__ float laux[4][64];
    const int lane = threadIdx.x & 63;
    const int wid  = threadIdx.x >> 6;
    float aux_acc = 0.f;
    const int tbase = blockIdx.x * 16 + wid * 4;

    for (int tt = 0; tt < 4; ++tt) {
        const int t = tbase + tt;
        double lg = 0.0;
        for (int ksi = 0; ksi < KS; ++ksi)
            lg += part[((size_t)ksi * T_TOKENS + t) * N_EXP + lane];

        // softmax max (f64 compare exact), exp/sum in f32
        double m = lg;
#pragma unroll
        for (int off = 32; off; off >>= 1) m = fmax(m, __shfl_xor(m, off));
        const float p = __expf((float)(lg - m));
        float s = p;
#pragma unroll
        for (int off = 32; off; off >>= 1) s += __shfl_xor(s, off);
        const float inv_s = 1.f / s;
        aux_acc += p * inv_s;

        // top-8 on f64 logits (monotone with probs; ties -> lower index)
        double pv = lg;
        int    pi = lane;
        float myp = 0.f; int myi = 0; float tsum = 0.f;
#pragma unroll
        for (int r = 0; r < 8; ++r) {
            double bv = pv; int bi = pi;
#pragma unroll
            for (int off = 32; off; off >>= 1) {
                const double ov = __shfl_xor(bv, off);
                const int    oi = __shfl_xor(bi, off);
                if (ov > bv || (ov == bv && oi < bi)) { bv = ov; bi = oi; }
            }
            const float bp = __expf((float)(bv - m)) * inv_s;
            tsum += bp;
            if (lane == r)  { myp = bp; myi = bi; }
            if (lane == bi) pv = -1.0e300;
        }
        if (lane < 8) {
            out_idx[(size_t)t * 8 + lane] = (float)myi;
            out_w[(size_t)t * 8 + lane]   = myp / tsum;
        }
    }

    laux[wid][lane] = aux_acc;
    __syncthreads();
    if (threadIdx.x < 64)
        expsum[(size_t)blockIdx.x * 64 + threadIdx.x] =
            laux[0][threadIdx.x] + laux[1][threadIdx.x] +
            laux[2][threadIdx.x] + laux[3][threadIdx.x];
}

// ---------------------------------------------------------------------------
// Kernel 3: aux loss finalize. 1 block, 256 threads (4 slices x 64 experts).
// ---------------------------------------------------------------------------
__global__ __launch_bounds__(256) void k_aux(const float* __restrict__ expsum, int nb,
                                             float* __restrict__ out_aux) {
    __shared__ float l[4][64];
    const int lane  = threadIdx.x & 63;
    const int slice = threadIdx.x >> 6;
    float s = 0.f;
    for (int b = slice; b < nb; b += 4) s += expsum[(size_t)b * 64 + lane];
    l[slice][lane] = s;
    __syncthreads();
    if (threadIdx.x < 64) {
        const float tot = l[0][lane] + l[1][lane] + l[2][lane] + l[3][lane];
        const float avg = tot * (1.f / (float)T_TOKENS);
        float v = avg * avg;
#pragma unroll
        for (int off = 32; off; off >>= 1) v += __shfl_xor(v, off);
        if (lane == 0) out_aux[0] = (float)N_EXP * 0.001f * v;
    }
}

extern "C" void kernel_launch(void* const* d_in, const int* in_sizes, int n_in,
                              void* d_out, int out_size, void* d_ws, size_t ws_size,
                              hipStream_t stream) {
    const float* h = (const float*)d_in[0];   // [8192,4096]
    const float* w = (const float*)d_in[1];   // [64,4096]
    float* out      = (float*)d_out;
    float* out_idx  = out;                    // 65536 (indices as float)
    float* out_w    = out + 65536;            // 65536
    float* out_aux  = out + 131072;           // 1

    const size_t part_elems = (size_t)T_TOKENS * N_EXP;      // per k-split
    const int NB2 = 512;                                      // router blocks
    int KS = 16;
    while (KS > 1 &&
           ((size_t)KS * part_elems * 8 + (size_t)NB2 * 64 * 4) > ws_size)
        KS >>= 1;

    double* part   = (double*)d_ws;
    float*  expsum = (float*)(part + (size_t)KS * part_elems);
    const int ks_len = D_MODEL / KS;

    dim3 g1(128, KS);
    k_gemm<<<g1, 64, 0, stream>>>(h, w, part, ks_len);
    k_router<<<NB2, 256, 0, stream>>>(part, KS, out_idx, out_w, expsum);
    k_aux<<<1, 256, 0, stream>>>(expsum, NB2, out_aux);
}